// Round 1
// baseline (450.765 us; speedup 1.0000x reference)
//
#include <hip/hip_runtime.h>

#define NROWS 8192
#define DDIM 128

typedef unsigned short u16;
typedef unsigned int u32;
typedef unsigned long long u64;
typedef __attribute__((ext_vector_type(4))) unsigned int u32x4;
typedef __attribute__((ext_vector_type(4))) float f32x4;
typedef __attribute__((ext_vector_type(2))) float f32x2;
typedef __attribute__((ext_vector_type(8))) short short8;

__device__ __forceinline__ u16 f32_to_bf16(float f){
  u32 u = __float_as_uint(f);
  u32 r = (u + 0x7FFFu + ((u >> 16) & 1u)) >> 16;
  return (u16)r;
}
__device__ __forceinline__ float bf16_to_f32(u16 h){ return __uint_as_float(((u32)h) << 16); }

// ---------------- kernel 1: bf16 hi/lo split + row sum-of-squares ----------------
__global__ __launch_bounds__(256) void split_kernel(const float* __restrict__ in,
                                                    u16* __restrict__ hi, u16* __restrict__ lo,
                                                    float* __restrict__ sq){
  int tid = threadIdx.x;
  int w = tid >> 6, lane = tid & 63;
  int row = blockIdx.x * 4 + w;
  f32x2 x = *(const f32x2*)(in + (size_t)row * DDIM + lane * 2);
  u16 h0 = f32_to_bf16(x.x); float h0f = bf16_to_f32(h0);
  u16 l0 = f32_to_bf16(x.x - h0f);
  u16 h1 = f32_to_bf16(x.y); float h1f = bf16_to_f32(h1);
  u16 l1 = f32_to_bf16(x.y - h1f);
  u32 hv = (u32)h0 | ((u32)h1 << 16);
  u32 lv = (u32)l0 | ((u32)l1 << 16);
  *(u32*)(hi + (size_t)row * DDIM + lane * 2) = hv;
  *(u32*)(lo + (size_t)row * DDIM + lane * 2) = lv;
  float s = x.x * x.x + x.y * x.y;
  #pragma unroll
  for (int m = 32; m >= 1; m >>= 1) s += __shfl_xor(s, m, 64);
  if (lane == 0) sq[row] = s;
}

// ---------------- kernel 2: tiled MFMA distance + fused hardest-pos/neg mining ----------------
__global__ __launch_bounds__(256) void dist_kernel(
    const u16* __restrict__ Ahi, const u16* __restrict__ Alo,
    const float* __restrict__ sq, const int* __restrict__ tgt,
    float* __restrict__ dist, u64* __restrict__ pos_key, u64* __restrict__ neg_key)
{
  __shared__ u16 sAhi[128 * 128];
  __shared__ u16 sAlo[128 * 128];
  __shared__ u16 sBhi[128 * 128];
  __shared__ u16 sBlo[128 * 128];
  __shared__ float s_sq[256];
  __shared__ int   s_t[256];

  const int bi = blockIdx.y, bj = blockIdx.x;
  const int tid = threadIdx.x;

  // ---- stage global -> LDS (XOR-swizzled rows: byte ^= (row&7)<<4) ----
  {
    char* dA0 = (char*)sAhi; char* dA1 = (char*)sAlo;
    char* dB0 = (char*)sBhi; char* dB1 = (char*)sBlo;
    #pragma unroll
    for (int i = 0; i < 8; ++i){
      int chunk = i * 256 + tid;
      int row = chunk >> 4;
      int c16 = chunk & 15;
      int dst = row * 256 + ((c16 * 16) ^ ((row & 7) << 4));
      size_t srcA = (size_t)(bi * 128 + row) * DDIM + c16 * 8;
      size_t srcB = (size_t)(bj * 128 + row) * DDIM + c16 * 8;
      *(u32x4*)(dA0 + dst) = *(const u32x4*)(Ahi + srcA);
      *(u32x4*)(dA1 + dst) = *(const u32x4*)(Alo + srcA);
      *(u32x4*)(dB0 + dst) = *(const u32x4*)(Ahi + srcB);
      *(u32x4*)(dB1 + dst) = *(const u32x4*)(Alo + srcB);
    }
    if (tid < 128){ s_sq[tid] = sq[bi * 128 + tid]; s_t[tid] = tgt[bi * 128 + tid]; }
    else { int c = tid - 128; s_sq[128 + c] = sq[bj * 128 + c]; s_t[128 + c] = tgt[bj * 128 + c]; }
  }
  __syncthreads();

  const int w = tid >> 6, lane = tid & 63;
  const int wr = w >> 1, wc = w & 1;      // 2x2 waves, each owns 64x64
  const int lr = lane & 15, g = lane >> 4;

  f32x4 acc[4][4] = {};

  const char* bufs[3][2] = {
    {(const char*)sAhi, (const char*)sBhi},   // hi*hi
    {(const char*)sAhi, (const char*)sBlo},   // hi*lo
    {(const char*)sAlo, (const char*)sBhi}};  // lo*hi

  #pragma unroll
  for (int pass = 0; pass < 3; ++pass){
    const char* pa = bufs[pass][0];
    const char* pb = bufs[pass][1];
    #pragma unroll
    for (int kk = 0; kk < 4; ++kk){
      short8 af[4], bfr[4];
      #pragma unroll
      for (int m = 0; m < 4; ++m){
        int r = wr * 64 + m * 16 + lr;
        af[m] = *(const short8*)(pa + r * 256 + ((kk * 64 + g * 16) ^ ((r & 7) << 4)));
      }
      #pragma unroll
      for (int n = 0; n < 4; ++n){
        int r = wc * 64 + n * 16 + lr;
        bfr[n] = *(const short8*)(pb + r * 256 + ((kk * 64 + g * 16) ^ ((r & 7) << 4)));
      }
      #pragma unroll
      for (int m = 0; m < 4; ++m)
        #pragma unroll
        for (int n = 0; n < 4; ++n)
          acc[m][n] = __builtin_amdgcn_mfma_f32_16x16x32_bf16(af[m], bfr[n], acc[m][n], 0, 0, 0);
    }
  }

  // ---- epilogue: d2 -> dist, write, masked row max/min with argidx ----
  float sqc[4]; int tc[4]; int gcol[4];
  #pragma unroll
  for (int n = 0; n < 4; ++n){
    int cl = wc * 64 + n * 16 + lr;
    sqc[n] = s_sq[128 + cl]; tc[n] = s_t[128 + cl]; gcol[n] = bj * 128 + cl;
  }
  #pragma unroll
  for (int m = 0; m < 4; ++m){
    int rl0 = wr * 64 + m * 16 + g * 4;
    float sqr[4]; int trw[4];
    #pragma unroll
    for (int r = 0; r < 4; ++r){ sqr[r] = s_sq[rl0 + r]; trw[r] = s_t[rl0 + r]; }
    float bpv[4], bnv[4]; int bpc[4], bnc[4];
    #pragma unroll
    for (int r = 0; r < 4; ++r){ bpv[r] = -1.f; bpc[r] = 0x7FFFFFFF; bnv[r] = 3.0e38f; bnc[r] = 0x7FFFFFFF; }
    #pragma unroll
    for (int n = 0; n < 4; ++n){
      #pragma unroll
      for (int r = 0; r < 4; ++r){
        float dot = acc[m][n][r];
        float d2 = sqr[r] + sqc[n] - 2.f * dot;
        d2 = fminf(fmaxf(d2, 1e-12f), 1e12f);
        float dd = sqrtf(d2);
        dist[(size_t)(bi * 128 + rl0 + r) * NROWS + gcol[n]] = dd;
        if (trw[r] == tc[n]){
          if (dd > bpv[r]){ bpv[r] = dd; bpc[r] = gcol[n]; }
        } else {
          if (dd < bnv[r]){ bnv[r] = dd; bnc[r] = gcol[n]; }
        }
      }
    }
    #pragma unroll
    for (int r = 0; r < 4; ++r){
      #pragma unroll
      for (int msk = 1; msk < 16; msk <<= 1){
        float ov = __shfl_xor(bpv[r], msk, 64); int oc = __shfl_xor(bpc[r], msk, 64);
        if (ov > bpv[r] || (ov == bpv[r] && oc < bpc[r])){ bpv[r] = ov; bpc[r] = oc; }
        ov = __shfl_xor(bnv[r], msk, 64); oc = __shfl_xor(bnc[r], msk, 64);
        if (ov < bnv[r] || (ov == bnv[r] && oc < bnc[r])){ bnv[r] = ov; bnc[r] = oc; }
      }
      if (lr == 0){
        int grow = bi * 128 + rl0 + r;
        if (bpv[r] >= 0.f)
          atomicMax(&pos_key[grow],
                    ((u64)__float_as_uint(bpv[r]) << 32) | (u64)(0xFFFFFFFFu - (u32)bpc[r]));
        if (bnv[r] < 3.0e38f)
          atomicMin(&neg_key[grow],
                    ((u64)__float_as_uint(bnv[r]) << 32) | (u64)(u32)bnc[r]);
      }
    }
  }
}

// ---------------- kernel 3: decode packed keys ----------------
__global__ __launch_bounds__(256) void decode_kernel(const u64* __restrict__ pk, const u64* __restrict__ nk,
                                                     float* __restrict__ ap, float* __restrict__ an,
                                                     int* __restrict__ p2, int* __restrict__ n1){
  int i = blockIdx.x * 256 + threadIdx.x;
  u64 p = pk[i], q = nk[i];
  ap[i] = __uint_as_float((u32)(p >> 32));
  p2[i] = (int)(0xFFFFFFFFu - (u32)(p & 0xFFFFFFFFu));
  an[i] = __uint_as_float((u32)(q >> 32));
  n1[i] = (int)(u32)(q & 0xFFFFFFFFu);
}

// ---------------- kernel 4: gathers + hinge losses + prec (deterministic single block) ----------------
__global__ __launch_bounds__(256) void final_kernel(const float* __restrict__ ap, const float* __restrict__ an,
                                                    const int* __restrict__ p2, const int* __restrict__ n1,
                                                    float* __restrict__ out){
  __shared__ float r1[256], r2[256], r3[256]; __shared__ int r4[256];
  int tid = threadIdx.x;
  float s1 = 0.f, s2 = 0.f, s3 = 0.f; int pc = 0;
  for (int i = tid; i < NROWS; i += 256){
    float a = ap[i], b = an[i];
    float n12 = an[n1[i]];
    float p12 = ap[p2[i]];
    s1 += fmaxf(a - b, 0.f);
    s2 += fmaxf(a - n12, 0.f);
    s3 += fmaxf(p12 - b, 0.f);
    pc += (b > a) ? 1 : 0;
  }
  r1[tid] = s1; r2[tid] = s2; r3[tid] = s3; r4[tid] = pc;
  __syncthreads();
  for (int s = 128; s > 0; s >>= 1){
    if (tid < s){ r1[tid] += r1[tid + s]; r2[tid] += r2[tid + s]; r3[tid] += r3[tid + s]; r4[tid] += r4[tid + s]; }
    __syncthreads();
  }
  if (tid == 0){
    float inv = 1.f / (float)NROWS;
    out[0] = r1[0] * inv + 0.1f * (r2[0] * inv) + 0.1f * (r3[0] * inv);
    out[1] = (float)r4[0] * inv;
  }
}

extern "C" void kernel_launch(void* const* d_in, const int* in_sizes, int n_in,
                              void* d_out, int out_size, void* d_ws, size_t ws_size,
                              hipStream_t stream){
  const float* inputs = (const float*)d_in[0];
  const int* targets = (const int*)d_in[1];
  // d_in[2] (cids) is unused by the reference computation
  float* out = (float*)d_out;
  char* ws = (char*)d_ws;

  u16* Ahi = (u16*)ws;                                   // 2 MiB
  u16* Alo = (u16*)(ws + (2u << 20));                    // 2 MiB
  float* sq = (float*)(ws + (4u << 20));                 // 32 KiB
  u64* pos_key = (u64*)(ws + (4u << 20) + (64u << 10));  // 64 KiB
  u64* neg_key = (u64*)(ws + (4u << 20) + (128u << 10)); // 64 KiB
  float* ap = (float*)(ws + (4u << 20) + (192u << 10));
  float* an = (float*)(ws + (4u << 20) + (224u << 10));
  int* p2 = (int*)(ws + (4u << 20) + (256u << 10));
  int* n1 = (int*)(ws + (4u << 20) + (288u << 10));

  hipMemsetAsync(pos_key, 0x00, NROWS * sizeof(u64), stream);
  hipMemsetAsync(neg_key, 0xFF, NROWS * sizeof(u64), stream);

  split_kernel<<<NROWS / 4, 256, 0, stream>>>(inputs, Ahi, Alo, sq);
  dist_kernel<<<dim3(64, 64), 256, 0, stream>>>(Ahi, Alo, sq, targets, out + 2, pos_key, neg_key);
  decode_kernel<<<NROWS / 256, 256, 0, stream>>>(pos_key, neg_key, ap, an, p2, n1);
  final_kernel<<<1, 256, 0, stream>>>(ap, an, p2, n1, out);
}

// Round 2
// 305.597 us; speedup vs baseline: 1.4750x; 1.4750x over previous
//
#include <hip/hip_runtime.h>

#define NROWS 8192
#define DDIM 128

typedef unsigned short u16;
typedef unsigned int u32;
typedef unsigned long long u64;
typedef __attribute__((ext_vector_type(4))) float f32x4;
typedef __attribute__((ext_vector_type(8))) short short8;

__device__ __forceinline__ u16 f32_to_bf16(float f){
  u32 u = __float_as_uint(f);
  u32 r = (u + 0x7FFFu + ((u >> 16) & 1u)) >> 16;
  return (u16)r;
}
__device__ __forceinline__ float bf16_to_f32(u16 h){ return __uint_as_float(((u32)h) << 16); }

// ---------------- kernel 1: split f32 -> bf16 hi/lo, packed in MFMA-fragment order ----------------
// Packed layout: frag[((panel*4 + kk)*64 + g*16 + lr) * 8 + e]
//   panel = row/16, lr = row%16, kk = k/32, g = (k/8)%4, e = k%8
// A wave loading fragment (panel,kk) reads 64 lanes x 16B = 1024B contiguous.
__global__ __launch_bounds__(256) void pack_kernel(const float* __restrict__ in,
                                                   u16* __restrict__ phi, u16* __restrict__ plo,
                                                   float* __restrict__ sq){
  int t = blockIdx.x * 256 + threadIdx.x;
  int r = t >> 4, s = t & 15;                  // row, 8-elem segment
  const float* src = in + (size_t)r * DDIM + s * 8;
  f32x4 a = *(const f32x4*)(src);
  f32x4 b = *(const f32x4*)(src + 4);
  float x[8] = {a.x, a.y, a.z, a.w, b.x, b.y, b.z, b.w};
  short8 hv, lv;
  float ss = 0.f;
  #pragma unroll
  for (int j = 0; j < 8; ++j){
    u16 h = f32_to_bf16(x[j]);
    u16 l = f32_to_bf16(x[j] - bf16_to_f32(h));
    hv[j] = (short)h; lv[j] = (short)l;
    ss += x[j] * x[j];
  }
  size_t dst = (((size_t)(r >> 4) * 4 + (s >> 2)) * 64 + (s & 3) * 16 + (r & 15)) * 8;
  *(short8*)(phi + dst) = hv;
  *(short8*)(plo + dst) = lv;
  // sum-of-squares across the 16 threads of this row (lanes are contiguous)
  #pragma unroll
  for (int m = 1; m < 16; m <<= 1) ss += __shfl_xor(ss, m, 64);
  if (s == 0) sq[r] = ss;
}

// ---------------- kernel 2: LDS-free MFMA distance + fused hardest-pos/neg mining ----------------
__global__ __launch_bounds__(256, 3) void dist_kernel(
    const u16* __restrict__ phi, const u16* __restrict__ plo,
    const float* __restrict__ sq, const int* __restrict__ tgt,
    float* __restrict__ dist, u64* __restrict__ pos_key, u64* __restrict__ neg_key)
{
  // XCD-aware swizzle: 4096 blocks, 8 XCDs -> each XCD gets 512 contiguous tiles (8 bi-rows)
  int id = blockIdx.x;
  int swz = (id & 7) * 512 + (id >> 3);
  const int bi = swz >> 6, bj = swz & 63;

  const int tid = threadIdx.x;
  const int w = tid >> 6, lane = tid & 63;
  const int wr = w >> 1, wc = w & 1;           // 2x2 waves, each owns 64x64 output
  const int lr = lane & 15, g = lane >> 4;

  f32x4 acc[4][4] = {};

  #pragma unroll
  for (int kk = 0; kk < 4; ++kk){
    short8 ah[4], al[4], bh[4], bl[4];
    #pragma unroll
    for (int m = 0; m < 4; ++m){
      size_t offA = ((size_t)(((bi * 8 + wr * 4 + m) * 4 + kk) * 64) + lane) * 8;
      ah[m] = *(const short8*)(phi + offA);
      al[m] = *(const short8*)(plo + offA);
      size_t offB = ((size_t)(((bj * 8 + wc * 4 + m) * 4 + kk) * 64) + lane) * 8;
      bh[m] = *(const short8*)(phi + offB);
      bl[m] = *(const short8*)(plo + offB);
    }
    #pragma unroll
    for (int m = 0; m < 4; ++m)
      #pragma unroll
      for (int n = 0; n < 4; ++n){
        acc[m][n] = __builtin_amdgcn_mfma_f32_16x16x32_bf16(ah[m], bh[n], acc[m][n], 0, 0, 0);
        acc[m][n] = __builtin_amdgcn_mfma_f32_16x16x32_bf16(ah[m], bl[n], acc[m][n], 0, 0, 0);
        acc[m][n] = __builtin_amdgcn_mfma_f32_16x16x32_bf16(al[m], bh[n], acc[m][n], 0, 0, 0);
      }
  }

  // ---- epilogue: d2 -> dist, nontemporal write, masked row max/min with argidx ----
  float sqc[4]; int tc[4]; int gcol[4];
  #pragma unroll
  for (int n = 0; n < 4; ++n){
    int cl = bj * 128 + wc * 64 + n * 16 + lr;
    sqc[n] = sq[cl]; tc[n] = tgt[cl]; gcol[n] = cl;
  }
  #pragma unroll
  for (int m = 0; m < 4; ++m){
    int rl0 = wr * 64 + m * 16 + g * 4;
    float sqr[4]; int trw[4];
    #pragma unroll
    for (int r = 0; r < 4; ++r){
      int grow = bi * 128 + rl0 + r;
      sqr[r] = sq[grow]; trw[r] = tgt[grow];
    }
    float bpv[4], bnv[4]; int bpc[4], bnc[4];
    #pragma unroll
    for (int r = 0; r < 4; ++r){ bpv[r] = -1.f; bpc[r] = 0x7FFFFFFF; bnv[r] = 3.0e38f; bnc[r] = 0x7FFFFFFF; }
    #pragma unroll
    for (int n = 0; n < 4; ++n){
      #pragma unroll
      for (int r = 0; r < 4; ++r){
        float dot = acc[m][n][r];
        float d2 = sqr[r] + sqc[n] - 2.f * dot;
        d2 = fminf(fmaxf(d2, 1e-12f), 1e12f);
        float dd = sqrtf(d2);
        __builtin_nontemporal_store(dd, dist + (size_t)(bi * 128 + rl0 + r) * NROWS + gcol[n]);
        if (trw[r] == tc[n]){
          if (dd > bpv[r]){ bpv[r] = dd; bpc[r] = gcol[n]; }
        } else {
          if (dd < bnv[r]){ bnv[r] = dd; bnc[r] = gcol[n]; }
        }
      }
    }
    #pragma unroll
    for (int r = 0; r < 4; ++r){
      #pragma unroll
      for (int msk = 1; msk < 16; msk <<= 1){
        float ov = __shfl_xor(bpv[r], msk, 64); int oc = __shfl_xor(bpc[r], msk, 64);
        if (ov > bpv[r] || (ov == bpv[r] && oc < bpc[r])){ bpv[r] = ov; bpc[r] = oc; }
        ov = __shfl_xor(bnv[r], msk, 64); oc = __shfl_xor(bnc[r], msk, 64);
        if (ov < bnv[r] || (ov == bnv[r] && oc < bnc[r])){ bnv[r] = ov; bnc[r] = oc; }
      }
      if (lr == 0){
        int grow = bi * 128 + rl0 + r;
        if (bpv[r] >= 0.f)
          atomicMax(&pos_key[grow],
                    ((u64)__float_as_uint(bpv[r]) << 32) | (u64)(0xFFFFFFFFu - (u32)bpc[r]));
        if (bnv[r] < 3.0e38f)
          atomicMin(&neg_key[grow],
                    ((u64)__float_as_uint(bnv[r]) << 32) | (u64)(u32)bnc[r]);
      }
    }
  }
}

// ---------------- kernel 3: decode packed keys ----------------
__global__ __launch_bounds__(256) void decode_kernel(const u64* __restrict__ pk, const u64* __restrict__ nk,
                                                     float* __restrict__ ap, float* __restrict__ an,
                                                     int* __restrict__ p2, int* __restrict__ n1){
  int i = blockIdx.x * 256 + threadIdx.x;
  u64 p = pk[i], q = nk[i];
  ap[i] = __uint_as_float((u32)(p >> 32));
  p2[i] = (int)(0xFFFFFFFFu - (u32)(p & 0xFFFFFFFFu));
  an[i] = __uint_as_float((u32)(q >> 32));
  n1[i] = (int)(u32)(q & 0xFFFFFFFFu);
}

// ---------------- kernel 4: gathers + hinge losses + prec (deterministic single block) ----------------
__global__ __launch_bounds__(256) void final_kernel(const float* __restrict__ ap, const float* __restrict__ an,
                                                    const int* __restrict__ p2, const int* __restrict__ n1,
                                                    float* __restrict__ out){
  __shared__ float r1[256], r2[256], r3[256]; __shared__ int r4[256];
  int tid = threadIdx.x;
  float s1 = 0.f, s2 = 0.f, s3 = 0.f; int pc = 0;
  for (int i = tid; i < NROWS; i += 256){
    float a = ap[i], b = an[i];
    float n12 = an[n1[i]];
    float p12 = ap[p2[i]];
    s1 += fmaxf(a - b, 0.f);
    s2 += fmaxf(a - n12, 0.f);
    s3 += fmaxf(p12 - b, 0.f);
    pc += (b > a) ? 1 : 0;
  }
  r1[tid] = s1; r2[tid] = s2; r3[tid] = s3; r4[tid] = pc;
  __syncthreads();
  for (int s = 128; s > 0; s >>= 1){
    if (tid < s){ r1[tid] += r1[tid + s]; r2[tid] += r2[tid + s]; r3[tid] += r3[tid + s]; r4[tid] += r4[tid + s]; }
    __syncthreads();
  }
  if (tid == 0){
    float inv = 1.f / (float)NROWS;
    out[0] = r1[0] * inv + 0.1f * (r2[0] * inv) + 0.1f * (r3[0] * inv);
    out[1] = (float)r4[0] * inv;
  }
}

extern "C" void kernel_launch(void* const* d_in, const int* in_sizes, int n_in,
                              void* d_out, int out_size, void* d_ws, size_t ws_size,
                              hipStream_t stream){
  const float* inputs = (const float*)d_in[0];
  const int* targets = (const int*)d_in[1];
  // d_in[2] (cids) is unused by the reference computation
  float* out = (float*)d_out;
  char* ws = (char*)d_ws;

  u16* phi = (u16*)ws;                                   // 2 MiB packed hi
  u16* plo = (u16*)(ws + (2u << 20));                    // 2 MiB packed lo
  float* sq = (float*)(ws + (4u << 20));                 // 32 KiB
  u64* pos_key = (u64*)(ws + (4u << 20) + (64u << 10));  // 64 KiB
  u64* neg_key = (u64*)(ws + (4u << 20) + (128u << 10)); // 64 KiB
  float* ap = (float*)(ws + (4u << 20) + (192u << 10));
  float* an = (float*)(ws + (4u << 20) + (224u << 10));
  int* p2 = (int*)(ws + (4u << 20) + (256u << 10));
  int* n1 = (int*)(ws + (4u << 20) + (288u << 10));

  hipMemsetAsync(pos_key, 0x00, NROWS * sizeof(u64), stream);
  hipMemsetAsync(neg_key, 0xFF, NROWS * sizeof(u64), stream);

  pack_kernel<<<(NROWS * 16) / 256, 256, 0, stream>>>(inputs, phi, plo, sq);
  dist_kernel<<<64 * 64, 256, 0, stream>>>(phi, plo, sq, targets, out + 2, pos_key, neg_key);
  decode_kernel<<<NROWS / 256, 256, 0, stream>>>(pos_key, neg_key, ap, an, p2, n1);
  final_kernel<<<1, 256, 0, stream>>>(ap, an, p2, n1, out);
}

// Round 4
// 157.744 us; speedup vs baseline: 2.8576x; 1.9373x over previous
//
#include <hip/hip_runtime.h>

#define NROWS 8192
#define DDIM 128

typedef unsigned short u16;
typedef unsigned int u32;
typedef unsigned long long u64;
typedef __attribute__((ext_vector_type(4))) float f32x4;
typedef __attribute__((ext_vector_type(2))) float f32x2;
typedef __attribute__((ext_vector_type(4))) int i32x4;
typedef __attribute__((ext_vector_type(8))) short short8;

__device__ __forceinline__ u16 f32_to_bf16(float f){
  u32 u = __float_as_uint(f);
  u32 r = (u + 0x7FFFu + ((u >> 16) & 1u)) >> 16;
  return (u16)r;
}
__device__ __forceinline__ float bf16_to_f32(u16 h){ return __uint_as_float(((u32)h) << 16); }

// ---------------- kernel 1: split f32 -> bf16 hi/lo, packed in MFMA-fragment order ----------------
__global__ __launch_bounds__(256) void pack_kernel(const float* __restrict__ in,
                                                   u16* __restrict__ phi, u16* __restrict__ plo,
                                                   float* __restrict__ sq){
  int t = blockIdx.x * 256 + threadIdx.x;
  int r = t >> 4, s = t & 15;                  // row, 8-elem segment
  const float* src = in + (size_t)r * DDIM + s * 8;
  f32x4 a = *(const f32x4*)(src);
  f32x4 b = *(const f32x4*)(src + 4);
  float x[8] = {a.x, a.y, a.z, a.w, b.x, b.y, b.z, b.w};
  short8 hv, lv;
  float ss = 0.f;
  #pragma unroll
  for (int j = 0; j < 8; ++j){
    u16 h = f32_to_bf16(x[j]);
    u16 l = f32_to_bf16(x[j] - bf16_to_f32(h));
    hv[j] = (short)h; lv[j] = (short)l;
    ss += x[j] * x[j];
  }
  size_t dst = (((size_t)(r >> 4) * 4 + (s >> 2)) * 64 + (s & 3) * 16 + (r & 15)) * 8;
  *(short8*)(phi + dst) = hv;
  *(short8*)(plo + dst) = lv;
  #pragma unroll
  for (int m = 1; m < 16; m <<= 1) ss += __shfl_xor(ss, m, 64);
  if (s == 0) sq[r] = ss;
}

// ---------------- kernel 2: LDS-free MFMA distance + fused mining (col-major-ownership layout) ----------------
__global__ __launch_bounds__(256, 3) void dist_kernel(
    const u16* __restrict__ phi, const u16* __restrict__ plo,
    const float* __restrict__ sq, const int* __restrict__ tgt,
    float* __restrict__ dist, u64* __restrict__ pos_key, u64* __restrict__ neg_key)
{
  int id = blockIdx.x;
  int swz = (id & 7) * 512 + (id >> 3);
  const int bi = swz >> 6, bj = swz & 63;

  const int tid = threadIdx.x;
  const int w = tid >> 6, lane = tid & 63;
  const int wr = w >> 1, wc = w & 1;           // 2x2 waves, each owns 64x64 output
  const int lr = lane & 15, g = lane >> 4;

  // Operands SWAPPED vs R2: acc[m][n] = mfma(B_frag, A_frag).
  // Output mapping: row = bi*128 + wr*64 + m*16 + lr  (lane&15)
  //                 col = bj*128 + wc*64 + n*16 + g*4 + r  (reg r, group g)
  f32x4 acc[4][4] = {};

  #pragma unroll
  for (int kk = 0; kk < 4; ++kk){
    short8 ah[4], al[4], bh[4], bl[4];
    #pragma unroll
    for (int m = 0; m < 4; ++m){
      size_t offA = ((size_t)(((bi * 8 + wr * 4 + m) * 4 + kk) * 64) + lane) * 8;
      ah[m] = *(const short8*)(phi + offA);
      al[m] = *(const short8*)(plo + offA);
      size_t offB = ((size_t)(((bj * 8 + wc * 4 + m) * 4 + kk) * 64) + lane) * 8;
      bh[m] = *(const short8*)(phi + offB);
      bl[m] = *(const short8*)(plo + offB);
    }
    #pragma unroll
    for (int m = 0; m < 4; ++m)
      #pragma unroll
      for (int n = 0; n < 4; ++n){
        acc[m][n] = __builtin_amdgcn_mfma_f32_16x16x32_bf16(bh[n], ah[m], acc[m][n], 0, 0, 0);
        acc[m][n] = __builtin_amdgcn_mfma_f32_16x16x32_bf16(bl[n], ah[m], acc[m][n], 0, 0, 0);
        acc[m][n] = __builtin_amdgcn_mfma_f32_16x16x32_bf16(bh[n], al[m], acc[m][n], 0, 0, 0);
      }
  }

  // ---- epilogue ----
  f32x4 sqc[4]; i32x4 tcv[4]; int cbase[4];
  #pragma unroll
  for (int n = 0; n < 4; ++n){
    cbase[n] = bj * 128 + wc * 64 + n * 16 + g * 4;
    sqc[n] = *(const f32x4*)(sq + cbase[n]);
    tcv[n] = *(const i32x4*)(tgt + cbase[n]);
  }
  #pragma unroll
  for (int m = 0; m < 4; ++m){
    const int grow = bi * 128 + wr * 64 + m * 16 + lr;
    const float sqr = sq[grow];
    const int tr = tgt[grow];
    float bpv = -1.f, bnv = 3.0e38f; int bpc = 0x7FFFFFFF, bnc = 0x7FFFFFFF;
    float* drow = dist + (size_t)grow * NROWS;
    #pragma unroll
    for (int n = 0; n < 4; ++n){
      f32x4 dd4;
      #pragma unroll
      for (int r = 0; r < 4; ++r){
        float d2 = sqr + sqc[n][r] - 2.f * acc[m][n][r];
        d2 = fminf(fmaxf(d2, 1e-12f), 1e12f);
        float dd = sqrtf(d2);
        dd4[r] = dd;
        if (tr == tcv[n][r]){
          if (dd > bpv){ bpv = dd; bpc = cbase[n] + r; }
        } else {
          if (dd < bnv){ bnv = dd; bnc = cbase[n] + r; }
        }
      }
      // dist base is out+2 (8B-aligned) -> use two 8B stores (dword-x2, naturally aligned)
      *(f32x2*)(drow + cbase[n])     = f32x2{dd4.x, dd4.y};
      *(f32x2*)(drow + cbase[n] + 2) = f32x2{dd4.z, dd4.w};
    }
    // reduce across the 4 g-groups (lanes lr, lr+16, lr+32, lr+48 hold the same row)
    #pragma unroll
    for (int msk = 16; msk <= 32; msk <<= 1){
      float ov = __shfl_xor(bpv, msk, 64); int oc = __shfl_xor(bpc, msk, 64);
      if (ov > bpv || (ov == bpv && oc < bpc)){ bpv = ov; bpc = oc; }
      ov = __shfl_xor(bnv, msk, 64); oc = __shfl_xor(bnc, msk, 64);
      if (ov < bnv || (ov == bnv && oc < bnc)){ bnv = ov; bnc = oc; }
    }
    if (g == 0){
      if (bpv >= 0.f)
        atomicMax(&pos_key[grow],
                  ((u64)__float_as_uint(bpv) << 32) | (u64)(0xFFFFFFFFu - (u32)bpc));
      if (bnv < 3.0e38f)
        atomicMin(&neg_key[grow],
                  ((u64)__float_as_uint(bnv) << 32) | (u64)(u32)bnc);
    }
  }
}

// ---------------- kernel 3: decode packed keys ----------------
__global__ __launch_bounds__(256) void decode_kernel(const u64* __restrict__ pk, const u64* __restrict__ nk,
                                                     float* __restrict__ ap, float* __restrict__ an,
                                                     int* __restrict__ p2, int* __restrict__ n1){
  int i = blockIdx.x * 256 + threadIdx.x;
  u64 p = pk[i], q = nk[i];
  ap[i] = __uint_as_float((u32)(p >> 32));
  p2[i] = (int)(0xFFFFFFFFu - (u32)(p & 0xFFFFFFFFu));
  an[i] = __uint_as_float((u32)(q >> 32));
  n1[i] = (int)(u32)(q & 0xFFFFFFFFu);
}

// ---------------- kernel 4: gathers + hinge losses + prec (deterministic single block) ----------------
__global__ __launch_bounds__(256) void final_kernel(const float* __restrict__ ap, const float* __restrict__ an,
                                                    const int* __restrict__ p2, const int* __restrict__ n1,
                                                    float* __restrict__ out){
  __shared__ float r1[256], r2[256], r3[256]; __shared__ int r4[256];
  int tid = threadIdx.x;
  float s1 = 0.f, s2 = 0.f, s3 = 0.f; int pc = 0;
  for (int i = tid; i < NROWS; i += 256){
    float a = ap[i], b = an[i];
    float n12 = an[n1[i]];
    float p12 = ap[p2[i]];
    s1 += fmaxf(a - b, 0.f);
    s2 += fmaxf(a - n12, 0.f);
    s3 += fmaxf(p12 - b, 0.f);
    pc += (b > a) ? 1 : 0;
  }
  r1[tid] = s1; r2[tid] = s2; r3[tid] = s3; r4[tid] = pc;
  __syncthreads();
  for (int s = 128; s > 0; s >>= 1){
    if (tid < s){ r1[tid] += r1[tid + s]; r2[tid] += r2[tid + s]; r3[tid] += r3[tid + s]; r4[tid] += r4[tid + s]; }
    __syncthreads();
  }
  if (tid == 0){
    float inv = 1.f / (float)NROWS;
    out[0] = r1[0] * inv + 0.1f * (r2[0] * inv) + 0.1f * (r3[0] * inv);
    out[1] = (float)r4[0] * inv;
  }
}

extern "C" void kernel_launch(void* const* d_in, const int* in_sizes, int n_in,
                              void* d_out, int out_size, void* d_ws, size_t ws_size,
                              hipStream_t stream){
  const float* inputs = (const float*)d_in[0];
  const int* targets = (const int*)d_in[1];
  float* out = (float*)d_out;
  char* ws = (char*)d_ws;

  u16* phi = (u16*)ws;                                   // 2 MiB packed hi
  u16* plo = (u16*)(ws + (2u << 20));                    // 2 MiB packed lo
  float* sq = (float*)(ws + (4u << 20));                 // 32 KiB
  u64* pos_key = (u64*)(ws + (4u << 20) + (64u << 10));  // 64 KiB
  u64* neg_key = (u64*)(ws + (4u << 20) + (128u << 10)); // 64 KiB
  float* ap = (float*)(ws + (4u << 20) + (192u << 10));
  float* an = (float*)(ws + (4u << 20) + (224u << 10));
  int* p2 = (int*)(ws + (4u << 20) + (256u << 10));
  int* n1 = (int*)(ws + (4u << 20) + (288u << 10));

  hipMemsetAsync(pos_key, 0x00, NROWS * sizeof(u64), stream);
  hipMemsetAsync(neg_key, 0xFF, NROWS * sizeof(u64), stream);

  pack_kernel<<<(NROWS * 16) / 256, 256, 0, stream>>>(inputs, phi, plo, sq);
  dist_kernel<<<64 * 64, 256, 0, stream>>>(phi, plo, sq, targets, out + 2, pos_key, neg_key);
  decode_kernel<<<NROWS / 256, 256, 0, stream>>>(pos_key, neg_key, ap, an, p2, n1);
  final_kernel<<<1, 256, 0, stream>>>(ap, an, p2, n1, out);
}